// Round 8
// baseline (822.416 us; speedup 1.0000x reference)
//
#include <hip/hip_runtime.h>
#include <hip/hip_bf16.h>
#include <math.h>

#define T 8
#define N 1024
#define D 128

constexpr float SCALE = 0.08838834764831845f; // 1/sqrt(128)

typedef __attribute__((ext_vector_type(8))) short short8;   // 8 bf16 (4 VGPRs)
typedef __attribute__((ext_vector_type(4))) float floatx4;  // MFMA acc / native float4

#define MFMA16(a, b, c) __builtin_amdgcn_mfma_f32_16x16x32_bf16((a), (b), (c), 0, 0, 0)

// ---------------- Kernel 0: X fp32 -> XB[t][n][d] bf16 ; XBTb hi/lo [t][n/8][d][8] bf16 ----------
__global__ __launch_bounds__(256) void convert_bf16(const float* __restrict__ X,
                                                    ushort* __restrict__ XB,
                                                    ushort* __restrict__ XBT_hi,
                                                    ushort* __restrict__ XBT_lo) {
    const int t  = blockIdx.y;
    const int n0 = blockIdx.x * 64;
    const int tid = threadIdx.x;

    __shared__ ushort Hi[128][66];
    __shared__ ushort Lo[128][66];

    #pragma unroll
    for (int r = 0; r < 8; ++r) {
        int idx = r * 256 + tid;            // 0..2047 float4 slots of this tile
        int nl  = idx >> 5;                 // 0..63  local node
        int c4  = idx & 31;                 // float4 column
        float4 v = *(const float4*)(X + ((size_t)t * N + n0 + nl) * D + c4 * 4);
        float vv[4] = {v.x, v.y, v.z, v.w};
        ushort4 o; ushort* op = (ushort*)&o;
        #pragma unroll
        for (int k = 0; k < 4; ++k) {
            __hip_bfloat16 h = __float2bfloat16(vv[k]);
            float hf = __bfloat162float(h);
            __hip_bfloat16 l = __float2bfloat16(vv[k] - hf);
            op[k] = *(ushort*)&h;
            Hi[c4 * 4 + k][nl] = *(ushort*)&h;
            Lo[c4 * 4 + k][nl] = *(ushort*)&l;
        }
        *(ushort4*)(XB + ((size_t)t * N + n0 + nl) * D + c4 * 4) = o;
    }
    __syncthreads();

    const int u  = tid & 31;                // uint column (2 nodes: n_lo = 2u, 2u+1)
    const int dr = tid >> 5;                // 0..7
    #pragma unroll
    for (int p = 0; p < 16; ++p) {
        int d = p * 8 + dr;
        uint hv = *(const uint*)&Hi[d][2 * u];
        uint lv = *(const uint*)&Lo[d][2 * u];
        int n_lo = 2 * u;
        int g8   = (n0 + n_lo) >> 3;        // k-group
        int pos  = n_lo & 7;                // 0,2,4,6 (uint stays in-group)
        size_t off = (((size_t)t * 128 + g8) * 128 + d) * 8 + pos;
        *(uint*)(XBT_hi + off) = hv;
        *(uint*)(XBT_lo + off) = lv;
    }
}

// ---------------- Kernel 0b: adj -> 16-bit column bitmask ----------------
__global__ __launch_bounds__(256) void pack_adj(const int* __restrict__ adj,
                                                ushort* __restrict__ Abits) {
    int g = blockIdx.x * 256 + threadIdx.x;   // 0..65535
    int i = g >> 6, w = g & 63;
    const int4* p4 = (const int4*)(adj + (size_t)i * N + w * 16);
    uint m16 = 0;
    #pragma unroll
    for (int v4 = 0; v4 < 4; ++v4) {
        int4 v = p4[v4];
        m16 |= (v.x != 0 ? 1u : 0u) << (v4 * 4 + 0);
        m16 |= (v.y != 0 ? 1u : 0u) << (v4 * 4 + 1);
        m16 |= (v.z != 0 ? 1u : 0u) << (v4 * 4 + 2);
        m16 |= (v.w != 0 ? 1u : 0u) << (v4 * 4 + 3);
    }
    Abits[g] = (ushort)m16;
}

// ---------------- Kernel 1: fused GAT row-block v4 — DIAGNOSTIC REP=5 ----------------
// r6 confirmed the TLP theory (-14us) but attn is still ~38us vs ~14us L2 floor.
// This round: REP=5 PMC capture on the v4 structure (same recipe as r4: memory
// clobber defeats CSE/DCE, rep barrier isolates; numerics idempotent). Decision
// tree pre-committed in journal: occupancy-still-low -> reg diet; VALU-high ->
// swapped-P register design; all-idle -> deeper PF; conflicts -> swizzle fix.
__global__ __launch_bounds__(512, 4) void attn_fused(const ushort* __restrict__ XB,
                                                     const ushort* __restrict__ XBT_hi,
                                                     const ushort* __restrict__ XBT_lo,
                                                     const ushort* __restrict__ Abits,
                                                     float* __restrict__ NF) {
    const int g  = blockIdx.x;
    const int t  = g & 7;              // XCD-aligned timestamp
    const int i0 = (g >> 3) * 16;
    const int tid  = threadIdx.x;
    const int wid  = tid >> 6;         // 0..7
    const int lane = tid & 63;
    const int m    = lane & 15;
    const int quad = lane >> 4;
    const int jbase = wid * 128;       // this wave's 128 score-cols

    __shared__ ushort Ph[16][1024];    // swizzled bf16 hi
    __shared__ ushort Plo[16][1024];   // swizzled bf16 lo
    float* red = (float*)&Ph[0][0];    // aliased: [0..127] rowmax, [128..255] rowsum

    const ushort* Xt = XB + (size_t)t * N * D;

    #pragma unroll 1
    for (int rep = 0; rep < 5; ++rep) {
    asm volatile("" ::: "memory");     // force re-load / re-compute each rep

    // A-fragments for this row tile (live through Phase 1 only)
    short8 afrag[4];
    {
        const ushort* pa = Xt + (size_t)(i0 + m) * D + quad * 8;
        #pragma unroll
        for (int kq = 0; kq < 4; ++kq) afrag[kq] = *(const short8*)(pa + kq * 32);
    }

    floatx4 acc[8];
    #pragma unroll
    for (int c = 0; c < 8; ++c) acc[c] = (floatx4){0.f, 0.f, 0.f, 0.f};

    // ---- Phase 1: scores (2-deep pipelined B loads), 8 col-tiles per wave ----
    short8 bfr[2][4];
    {
        const ushort* pb = Xt + (size_t)(jbase + m) * D + quad * 8;
        bfr[0][0] = *(const short8*)(pb);
        bfr[0][1] = *(const short8*)(pb + 32);
        bfr[0][2] = *(const short8*)(pb + 64);
        bfr[0][3] = *(const short8*)(pb + 96);
    }
    #pragma unroll
    for (int c = 0; c < 8; ++c) {
        if (c < 7) {
            const ushort* pb = Xt + (size_t)(jbase + 16 * (c + 1) + m) * D + quad * 8;
            bfr[(c + 1) & 1][0] = *(const short8*)(pb);
            bfr[(c + 1) & 1][1] = *(const short8*)(pb + 32);
            bfr[(c + 1) & 1][2] = *(const short8*)(pb + 64);
            bfr[(c + 1) & 1][3] = *(const short8*)(pb + 96);
        }
        acc[c] = MFMA16(afrag[0], bfr[c & 1][0], acc[c]);
        acc[c] = MFMA16(afrag[1], bfr[c & 1][1], acc[c]);
        acc[c] = MFMA16(afrag[2], bfr[c & 1][2], acc[c]);
        acc[c] = MFMA16(afrag[3], bfr[c & 1][3], acc[c]);
    }

    // ---- Phase 2: mask + scale (adjw loaded here — short live range) ----
    short8 adjw[4];   // words wid*8 .. wid*8+7 of each owned row
    #pragma unroll
    for (int q = 0; q < 4; ++q)
        adjw[q] = *(const short8*)(Abits + (size_t)(i0 + quad * 4 + q) * 64 + wid * 8);
    #pragma unroll
    for (int q = 0; q < 4; ++q) {
        #pragma unroll
        for (int c = 0; c < 8; ++c) {
            int aw = (ushort)adjw[q][c];
            acc[c][q] = ((aw >> m) & 1) ? acc[c][q] * SCALE : -1e12f;
        }
    }

    // ---- Softmax (max order exact; sum regrouped 8-serial + 8-wave) ----
    float mx[4], inv[4];
    #pragma unroll
    for (int q = 0; q < 4; ++q) {
        float v_ = acc[0][q];
        #pragma unroll
        for (int c = 1; c < 8; ++c) v_ = fmaxf(v_, acc[c][q]);
        v_ = fmaxf(v_, __shfl_xor(v_, 1));
        v_ = fmaxf(v_, __shfl_xor(v_, 2));
        v_ = fmaxf(v_, __shfl_xor(v_, 4));
        v_ = fmaxf(v_, __shfl_xor(v_, 8));
        mx[q] = v_;
    }
    if (m == 0) {
        #pragma unroll
        for (int q = 0; q < 4; ++q) red[wid * 16 + quad * 4 + q] = mx[q];
    }
    __syncthreads();
    #pragma unroll
    for (int q = 0; q < 4; ++q) {
        int r = quad * 4 + q;
        float v_ = red[r];
        #pragma unroll
        for (int w = 1; w < 8; ++w) v_ = fmaxf(v_, red[w * 16 + r]);
        mx[q] = v_;
    }

    float sm[4];
    #pragma unroll
    for (int q = 0; q < 4; ++q) {
        float s_ = 0.f;
        #pragma unroll
        for (int c = 0; c < 8; ++c) {
            float p = __expf(acc[c][q] - mx[q]);
            acc[c][q] = p;
            s_ += p;
        }
        s_ += __shfl_xor(s_, 1);
        s_ += __shfl_xor(s_, 2);
        s_ += __shfl_xor(s_, 4);
        s_ += __shfl_xor(s_, 8);
        sm[q] = s_;
    }
    if (m == 0) {
        #pragma unroll
        for (int q = 0; q < 4; ++q) red[128 + wid * 16 + quad * 4 + q] = sm[q];
    }
    __syncthreads();
    #pragma unroll
    for (int q = 0; q < 4; ++q) {
        int r = quad * 4 + q;
        float s_ = red[128 + r];
        #pragma unroll
        for (int w = 1; w < 8; ++w) s_ += red[128 + w * 16 + r];
        inv[q] = 1.f / s_;
    }
    __syncthreads();   // all red reads done before Ph overwrites the region

    // ---- Phase 3: P -> LDS (compensated bf16, XOR-swizzled 16B blocks) ----
    #pragma unroll
    for (int q = 0; q < 4; ++q) {
        const int row = quad * 4 + q;
        #pragma unroll
        for (int c = 0; c < 8; ++c) {
            const int col = jbase + 16 * c + m;
            const int sc = ((((col >> 3) ^ (row & 7)) << 3) | (col & 7));
            float p = acc[c][q] * inv[q];
            __hip_bfloat16 h = __float2bfloat16(p);
            float hf = __bfloat162float(h);
            __hip_bfloat16 l = __float2bfloat16(p - hf);
            Ph[row][sc]  = *(ushort*)&h;
            Plo[row][sc] = *(ushort*)&l;
        }
    }
    __syncthreads();

    // ---- Phase 4: NF = P * X (3-term compensated MFMA, depth-3 rolling prefetch) ----
    const int dcol = wid * 16 + m;
    const ushort* ph_base = XBT_hi + (size_t)t * 131072 + (size_t)dcol * 8;
    const ushort* pl_base = XBT_lo + (size_t)t * 131072 + (size_t)dcol * 8;
    short8 pfh[4], pfl[4];
#define PF(kq_)                                                                  \
    {                                                                            \
        const size_t off_ = (size_t)((kq_) * 4 + quad) * 1024;                   \
        pfh[(kq_) & 3] = *(const short8*)(ph_base + off_);                       \
        pfl[(kq_) & 3] = *(const short8*)(pl_base + off_);                       \
    }
    PF(0); PF(1); PF(2);

    floatx4 accN = (floatx4){0.f, 0.f, 0.f, 0.f};
    #pragma unroll
    for (int kq = 0; kq < 32; ++kq) {
        if (kq < 29) PF(kq + 3);
        const int blk = (((kq * 4 + quad) ^ (m & 7)) << 3);
        short8 ah = *(const short8*)&Ph[m][blk];
        short8 al = *(const short8*)&Plo[m][blk];
        accN = MFMA16(ah, pfh[kq & 3], accN);
        accN = MFMA16(ah, pfl[kq & 3], accN);
        accN = MFMA16(al, pfh[kq & 3], accN);
    }
#undef PF

    float* NFt = NF + (size_t)t * N * D;
    #pragma unroll
    for (int q = 0; q < 4; ++q)
        NFt[(size_t)(i0 + quad * 4 + q) * D + dcol] = accN[q];

    __syncthreads();   // rep isolation: all NF stores / LDS reads done before rep+1
    }  // rep
}

// ---------------- Kernel 2: fused temporal-gram + sigmoid + broadcast-expand ----------------
__global__ __launch_bounds__(256) void expand_fused(const float* __restrict__ NF,
                                                    float* __restrict__ out) {
    const int row = blockIdx.x;                 // 0..8191 = b*N + j
    const int b = row >> 10, j = row & 1023;
    const int tid = threadIdx.x;

    __shared__ float F[T][D + 4];               // +4 pad: lanes a=0..7 hit distinct banks
    __shared__ float w[T];

    {   // stage NF[a][j][:] — 256 threads x float4 = 4 KB
        int a = tid >> 5, c4 = (tid & 31) * 4;
        *(float4*)(&F[a][c4]) = *(const float4*)(NF + ((size_t)a * N + j) * D + c4);
    }
    __syncthreads();

    if (tid < T) {                              // 8 lanes: dot(F[tid], F[b])
        float s = 0.f;
        #pragma unroll
        for (int d4 = 0; d4 < 32; ++d4) {
            float4 fa = *(const float4*)(&F[tid][d4 * 4]);
            float4 fb = *(const float4*)(&F[b][d4 * 4]);
            s += fa.x * fb.x + fa.y * fb.y + fa.z * fb.z + fa.w * fb.w;
        }
        w[tid] = 1.f / (1.f + __expf(-s * SCALE));
    }
    __syncthreads();

    floatx4* orow = (floatx4*)(out + (size_t)row * (T * N));
    #pragma unroll
    for (int a = 0; a < T; ++a) {
        float wv = w[a];
        floatx4 v = {wv, wv, wv, wv};
        __builtin_nontemporal_store(v, orow + a * 256 + tid);
    }
}

extern "C" void kernel_launch(void* const* d_in, const int* in_sizes, int n_in,
                              void* d_out, int out_size, void* d_ws, size_t ws_size,
                              hipStream_t stream) {
    const float* X   = (const float*)d_in[0];   // [T,N,D] fp32
    const int*   adj = (const int*)d_in[1];     // [N,N] int32
    float* out = (float*)d_out;                 // [T*N, T*N] fp32

    float*  NF     = (float*)d_ws;                         // T*N*D fp32 (4 MB)
    ushort* XB     = (ushort*)(NF + (size_t)T * N * D);    // T*N*D bf16 (2 MB)
    ushort* XBT_hi = XB + (size_t)T * N * D;               // [t][n/8][d][8] bf16 (2 MB)
    ushort* XBT_lo = XBT_hi + (size_t)T * N * D;           // [t][n/8][d][8] bf16 (2 MB)
    ushort* Abits  = XBT_lo + (size_t)T * N * D;           // [N][64] u16 (128 KB)

    convert_bf16<<<dim3(N / 64, T), 256, 0, stream>>>(X, XB, XBT_hi, XBT_lo);
    pack_adj<<<dim3(N * 64 / 256), 256, 0, stream>>>(adj, Abits);
    attn_fused<<<dim3((N / 16) * T), 512, 0, stream>>>(XB, XBT_hi, XBT_lo, Abits, NF);
    expand_fused<<<dim3(T * N), 256, 0, stream>>>(NF, out);
}

// Round 9
// 407.195 us; speedup vs baseline: 2.0197x; 2.0197x over previous
//
#include <hip/hip_runtime.h>
#include <hip/hip_bf16.h>
#include <math.h>

#define T 8
#define N 1024
#define D 128

constexpr float SCALE = 0.08838834764831845f; // 1/sqrt(128)

typedef __attribute__((ext_vector_type(8))) short short8;   // 8 bf16 (4 VGPRs)
typedef __attribute__((ext_vector_type(4))) float floatx4;  // MFMA acc / native float4

#define MFMA16(a, b, c) __builtin_amdgcn_mfma_f32_16x16x32_bf16((a), (b), (c), 0, 0, 0)

// ---------------- Kernel 0: X fp32 -> XB[t][n][d] bf16 ; XBTb hi/lo [t][n/8][d][8] bf16 ----------
__global__ __launch_bounds__(256) void convert_bf16(const float* __restrict__ X,
                                                    ushort* __restrict__ XB,
                                                    ushort* __restrict__ XBT_hi,
                                                    ushort* __restrict__ XBT_lo) {
    const int t  = blockIdx.y;
    const int n0 = blockIdx.x * 64;
    const int tid = threadIdx.x;

    __shared__ ushort Hi[128][66];
    __shared__ ushort Lo[128][66];

    #pragma unroll
    for (int r = 0; r < 8; ++r) {
        int idx = r * 256 + tid;            // 0..2047 float4 slots of this tile
        int nl  = idx >> 5;                 // 0..63  local node
        int c4  = idx & 31;                 // float4 column
        float4 v = *(const float4*)(X + ((size_t)t * N + n0 + nl) * D + c4 * 4);
        float vv[4] = {v.x, v.y, v.z, v.w};
        ushort4 o; ushort* op = (ushort*)&o;
        #pragma unroll
        for (int k = 0; k < 4; ++k) {
            __hip_bfloat16 h = __float2bfloat16(vv[k]);
            float hf = __bfloat162float(h);
            __hip_bfloat16 l = __float2bfloat16(vv[k] - hf);
            op[k] = *(ushort*)&h;
            Hi[c4 * 4 + k][nl] = *(ushort*)&h;
            Lo[c4 * 4 + k][nl] = *(ushort*)&l;
        }
        *(ushort4*)(XB + ((size_t)t * N + n0 + nl) * D + c4 * 4) = o;
    }
    __syncthreads();

    const int u  = tid & 31;                // uint column (2 nodes: n_lo = 2u, 2u+1)
    const int dr = tid >> 5;                // 0..7
    #pragma unroll
    for (int p = 0; p < 16; ++p) {
        int d = p * 8 + dr;
        uint hv = *(const uint*)&Hi[d][2 * u];
        uint lv = *(const uint*)&Lo[d][2 * u];
        int n_lo = 2 * u;
        int g8   = (n0 + n_lo) >> 3;        // k-group
        int pos  = n_lo & 7;                // 0,2,4,6 (uint stays in-group)
        size_t off = (((size_t)t * 128 + g8) * 128 + d) * 8 + pos;
        *(uint*)(XBT_hi + off) = hv;
        *(uint*)(XBT_lo + off) = lv;
    }
}

// ---------------- Kernel 0b: adj -> 16-bit column bitmask ----------------
__global__ __launch_bounds__(256) void pack_adj(const int* __restrict__ adj,
                                                ushort* __restrict__ Abits) {
    int g = blockIdx.x * 256 + threadIdx.x;   // 0..65535
    int i = g >> 6, w = g & 63;
    const int4* p4 = (const int4*)(adj + (size_t)i * N + w * 16);
    uint m16 = 0;
    #pragma unroll
    for (int v4 = 0; v4 < 4; ++v4) {
        int4 v = p4[v4];
        m16 |= (v.x != 0 ? 1u : 0u) << (v4 * 4 + 0);
        m16 |= (v.y != 0 ? 1u : 0u) << (v4 * 4 + 1);
        m16 |= (v.z != 0 ? 1u : 0u) << (v4 * 4 + 2);
        m16 |= (v.w != 0 ? 1u : 0u) << (v4 * 4 + 3);
    }
    Abits[g] = (ushort)m16;
}

// ---------------- Kernel 1: fused GAT v4 — GRID-REP=5 production-codegen diagnostic ----------------
// r7's in-kernel REP loop perturbed regalloc (VGPR 64, ~60 dwords/thread spilled,
// WRITE 15x output) and invalidated itself. This round: REP via grid x5 with
// IDENTICAL kernel body — g = blockIdx.x & 511; only blockIdx < 512 stores NF
// (uniform runtime branch: compute not DCE-able, no write races). Copy k of work
// w sits on the same XCD (512 % 8 == 0). PMC now reflects production codegen:
// VGPR_Count + WRITE_SIZE give the spill verdict; Occupancy/VALUBusy/MfmaUtil
// pick the next fix per the pre-committed tree.
__global__ __launch_bounds__(512, 4) void attn_fused(const ushort* __restrict__ XB,
                                                     const ushort* __restrict__ XBT_hi,
                                                     const ushort* __restrict__ XBT_lo,
                                                     const ushort* __restrict__ Abits,
                                                     float* __restrict__ NF) {
    const int rep_g = blockIdx.x;
    const int g  = rep_g & 511;        // work id (5 copies)
    const bool writer = rep_g < 512;   // only copy 0 stores
    const int t  = g & 7;              // XCD-aligned timestamp
    const int i0 = (g >> 3) * 16;
    const int tid  = threadIdx.x;
    const int wid  = tid >> 6;         // 0..7
    const int lane = tid & 63;
    const int m    = lane & 15;
    const int quad = lane >> 4;
    const int jbase = wid * 128;       // this wave's 128 score-cols

    __shared__ ushort Ph[16][1024];    // swizzled bf16 hi
    __shared__ ushort Plo[16][1024];   // swizzled bf16 lo
    float* red = (float*)&Ph[0][0];    // aliased: [0..127] rowmax, [128..255] rowsum

    const ushort* Xt = XB + (size_t)t * N * D;

    // A-fragments for this row tile (live through Phase 1 only)
    short8 afrag[4];
    {
        const ushort* pa = Xt + (size_t)(i0 + m) * D + quad * 8;
        #pragma unroll
        for (int kq = 0; kq < 4; ++kq) afrag[kq] = *(const short8*)(pa + kq * 32);
    }

    floatx4 acc[8];
    #pragma unroll
    for (int c = 0; c < 8; ++c) acc[c] = (floatx4){0.f, 0.f, 0.f, 0.f};

    // ---- Phase 1: scores (2-deep pipelined B loads), 8 col-tiles per wave ----
    short8 bfr[2][4];
    {
        const ushort* pb = Xt + (size_t)(jbase + m) * D + quad * 8;
        bfr[0][0] = *(const short8*)(pb);
        bfr[0][1] = *(const short8*)(pb + 32);
        bfr[0][2] = *(const short8*)(pb + 64);
        bfr[0][3] = *(const short8*)(pb + 96);
    }
    #pragma unroll
    for (int c = 0; c < 8; ++c) {
        if (c < 7) {
            const ushort* pb = Xt + (size_t)(jbase + 16 * (c + 1) + m) * D + quad * 8;
            bfr[(c + 1) & 1][0] = *(const short8*)(pb);
            bfr[(c + 1) & 1][1] = *(const short8*)(pb + 32);
            bfr[(c + 1) & 1][2] = *(const short8*)(pb + 64);
            bfr[(c + 1) & 1][3] = *(const short8*)(pb + 96);
        }
        acc[c] = MFMA16(afrag[0], bfr[c & 1][0], acc[c]);
        acc[c] = MFMA16(afrag[1], bfr[c & 1][1], acc[c]);
        acc[c] = MFMA16(afrag[2], bfr[c & 1][2], acc[c]);
        acc[c] = MFMA16(afrag[3], bfr[c & 1][3], acc[c]);
    }

    // ---- Phase 2: mask + scale (adjw loaded here — short live range) ----
    short8 adjw[4];   // words wid*8 .. wid*8+7 of each owned row
    #pragma unroll
    for (int q = 0; q < 4; ++q)
        adjw[q] = *(const short8*)(Abits + (size_t)(i0 + quad * 4 + q) * 64 + wid * 8);
    #pragma unroll
    for (int q = 0; q < 4; ++q) {
        #pragma unroll
        for (int c = 0; c < 8; ++c) {
            int aw = (ushort)adjw[q][c];
            acc[c][q] = ((aw >> m) & 1) ? acc[c][q] * SCALE : -1e12f;
        }
    }

    // ---- Softmax (max order exact; sum regrouped 8-serial + 8-wave) ----
    float mx[4], inv[4];
    #pragma unroll
    for (int q = 0; q < 4; ++q) {
        float v_ = acc[0][q];
        #pragma unroll
        for (int c = 1; c < 8; ++c) v_ = fmaxf(v_, acc[c][q]);
        v_ = fmaxf(v_, __shfl_xor(v_, 1));
        v_ = fmaxf(v_, __shfl_xor(v_, 2));
        v_ = fmaxf(v_, __shfl_xor(v_, 4));
        v_ = fmaxf(v_, __shfl_xor(v_, 8));
        mx[q] = v_;
    }
    if (m == 0) {
        #pragma unroll
        for (int q = 0; q < 4; ++q) red[wid * 16 + quad * 4 + q] = mx[q];
    }
    __syncthreads();
    #pragma unroll
    for (int q = 0; q < 4; ++q) {
        int r = quad * 4 + q;
        float v_ = red[r];
        #pragma unroll
        for (int w = 1; w < 8; ++w) v_ = fmaxf(v_, red[w * 16 + r]);
        mx[q] = v_;
    }

    float sm[4];
    #pragma unroll
    for (int q = 0; q < 4; ++q) {
        float s_ = 0.f;
        #pragma unroll
        for (int c = 0; c < 8; ++c) {
            float p = __expf(acc[c][q] - mx[q]);
            acc[c][q] = p;
            s_ += p;
        }
        s_ += __shfl_xor(s_, 1);
        s_ += __shfl_xor(s_, 2);
        s_ += __shfl_xor(s_, 4);
        s_ += __shfl_xor(s_, 8);
        sm[q] = s_;
    }
    if (m == 0) {
        #pragma unroll
        for (int q = 0; q < 4; ++q) red[128 + wid * 16 + quad * 4 + q] = sm[q];
    }
    __syncthreads();
    #pragma unroll
    for (int q = 0; q < 4; ++q) {
        int r = quad * 4 + q;
        float s_ = red[128 + r];
        #pragma unroll
        for (int w = 1; w < 8; ++w) s_ += red[128 + w * 16 + r];
        inv[q] = 1.f / s_;
    }
    __syncthreads();   // all red reads done before Ph overwrites the region

    // ---- Phase 3: P -> LDS (compensated bf16, XOR-swizzled 16B blocks) ----
    #pragma unroll
    for (int q = 0; q < 4; ++q) {
        const int row = quad * 4 + q;
        #pragma unroll
        for (int c = 0; c < 8; ++c) {
            const int col = jbase + 16 * c + m;
            const int sc = ((((col >> 3) ^ (row & 7)) << 3) | (col & 7));
            float p = acc[c][q] * inv[q];
            __hip_bfloat16 h = __float2bfloat16(p);
            float hf = __bfloat162float(h);
            __hip_bfloat16 l = __float2bfloat16(p - hf);
            Ph[row][sc]  = *(ushort*)&h;
            Plo[row][sc] = *(ushort*)&l;
        }
    }
    __syncthreads();

    // ---- Phase 4: NF = P * X (3-term compensated MFMA, depth-3 rolling prefetch) ----
    const int dcol = wid * 16 + m;
    const ushort* ph_base = XBT_hi + (size_t)t * 131072 + (size_t)dcol * 8;
    const ushort* pl_base = XBT_lo + (size_t)t * 131072 + (size_t)dcol * 8;
    short8 pfh[4], pfl[4];
#define PF(kq_)                                                                  \
    {                                                                            \
        const size_t off_ = (size_t)((kq_) * 4 + quad) * 1024;                   \
        pfh[(kq_) & 3] = *(const short8*)(ph_base + off_);                       \
        pfl[(kq_) & 3] = *(const short8*)(pl_base + off_);                       \
    }
    PF(0); PF(1); PF(2);

    floatx4 accN = (floatx4){0.f, 0.f, 0.f, 0.f};
    #pragma unroll
    for (int kq = 0; kq < 32; ++kq) {
        if (kq < 29) PF(kq + 3);
        const int blk = (((kq * 4 + quad) ^ (m & 7)) << 3);
        short8 ah = *(const short8*)&Ph[m][blk];
        short8 al = *(const short8*)&Plo[m][blk];
        accN = MFMA16(ah, pfh[kq & 3], accN);
        accN = MFMA16(ah, pfl[kq & 3], accN);
        accN = MFMA16(al, pfh[kq & 3], accN);
    }
#undef PF

    if (writer) {
        float* NFt = NF + (size_t)t * N * D;
        #pragma unroll
        for (int q = 0; q < 4; ++q)
            NFt[(size_t)(i0 + quad * 4 + q) * D + dcol] = accN[q];
    }
}

// ---------------- Kernel 2: fused temporal-gram + sigmoid + broadcast-expand ----------------
__global__ __launch_bounds__(256) void expand_fused(const float* __restrict__ NF,
                                                    float* __restrict__ out) {
    const int row = blockIdx.x;                 // 0..8191 = b*N + j
    const int b = row >> 10, j = row & 1023;
    const int tid = threadIdx.x;

    __shared__ float F[T][D + 4];               // +4 pad: lanes a=0..7 hit distinct banks
    __shared__ float w[T];

    {   // stage NF[a][j][:] — 256 threads x float4 = 4 KB
        int a = tid >> 5, c4 = (tid & 31) * 4;
        *(float4*)(&F[a][c4]) = *(const float4*)(NF + ((size_t)a * N + j) * D + c4);
    }
    __syncthreads();

    if (tid < T) {                              // 8 lanes: dot(F[tid], F[b])
        float s = 0.f;
        #pragma unroll
        for (int d4 = 0; d4 < 32; ++d4) {
            float4 fa = *(const float4*)(&F[tid][d4 * 4]);
            float4 fb = *(const float4*)(&F[b][d4 * 4]);
            s += fa.x * fb.x + fa.y * fb.y + fa.z * fb.z + fa.w * fb.w;
        }
        w[tid] = 1.f / (1.f + __expf(-s * SCALE));
    }
    __syncthreads();

    floatx4* orow = (floatx4*)(out + (size_t)row * (T * N));
    #pragma unroll
    for (int a = 0; a < T; ++a) {
        float wv = w[a];
        floatx4 v = {wv, wv, wv, wv};
        __builtin_nontemporal_store(v, orow + a * 256 + tid);
    }
}

extern "C" void kernel_launch(void* const* d_in, const int* in_sizes, int n_in,
                              void* d_out, int out_size, void* d_ws, size_t ws_size,
                              hipStream_t stream) {
    const float* X   = (const float*)d_in[0];   // [T,N,D] fp32
    const int*   adj = (const int*)d_in[1];     // [N,N] int32
    float* out = (float*)d_out;                 // [T*N, T*N] fp32

    float*  NF     = (float*)d_ws;                         // T*N*D fp32 (4 MB)
    ushort* XB     = (ushort*)(NF + (size_t)T * N * D);    // T*N*D bf16 (2 MB)
    ushort* XBT_hi = XB + (size_t)T * N * D;               // [t][n/8][d][8] bf16 (2 MB)
    ushort* XBT_lo = XBT_hi + (size_t)T * N * D;           // [t][n/8][d][8] bf16 (2 MB)
    ushort* Abits  = XBT_lo + (size_t)T * N * D;           // [N][64] u16 (128 KB)

    convert_bf16<<<dim3(N / 64, T), 256, 0, stream>>>(X, XB, XBT_hi, XBT_lo);
    pack_adj<<<dim3(N * 64 / 256), 256, 0, stream>>>(adj, Abits);
    // GRID-REP=5: production codegen, 5x work, only first 512 blocks store NF.
    attn_fused<<<dim3((N / 16) * T * 5), 512, 0, stream>>>(XB, XBT_hi, XBT_lo, Abits, NF);
    expand_fused<<<dim3(T * N), 256, 0, stream>>>(NF, out);
}

// Round 10
// 345.026 us; speedup vs baseline: 2.3836x; 1.1802x over previous
//
#include <hip/hip_runtime.h>
#include <hip/hip_bf16.h>
#include <math.h>

#define T 8
#define N 1024
#define D 128

constexpr float SCALE = 0.08838834764831845f; // 1/sqrt(128)

typedef __attribute__((ext_vector_type(8))) short short8;   // 8 bf16 (4 VGPRs)
typedef __attribute__((ext_vector_type(4))) float floatx4;  // MFMA acc / native float4

#define MFMA16(a, b, c) __builtin_amdgcn_mfma_f32_16x16x32_bf16((a), (b), (c), 0, 0, 0)

// ---------------- Kernel 0: X fp32 -> XB[t][n][d] bf16 ; XBTb hi/lo [t][n/8][d][8] bf16 ----------
__global__ __launch_bounds__(256) void convert_bf16(const float* __restrict__ X,
                                                    ushort* __restrict__ XB,
                                                    ushort* __restrict__ XBT_hi,
                                                    ushort* __restrict__ XBT_lo) {
    const int t  = blockIdx.y;
    const int n0 = blockIdx.x * 64;
    const int tid = threadIdx.x;

    __shared__ ushort Hi[128][66];
    __shared__ ushort Lo[128][66];

    #pragma unroll
    for (int r = 0; r < 8; ++r) {
        int idx = r * 256 + tid;            // 0..2047 float4 slots of this tile
        int nl  = idx >> 5;                 // 0..63  local node
        int c4  = idx & 31;                 // float4 column
        float4 v = *(const float4*)(X + ((size_t)t * N + n0 + nl) * D + c4 * 4);
        float vv[4] = {v.x, v.y, v.z, v.w};
        ushort4 o; ushort* op = (ushort*)&o;
        #pragma unroll
        for (int k = 0; k < 4; ++k) {
            __hip_bfloat16 h = __float2bfloat16(vv[k]);
            float hf = __bfloat162float(h);
            __hip_bfloat16 l = __float2bfloat16(vv[k] - hf);
            op[k] = *(ushort*)&h;
            Hi[c4 * 4 + k][nl] = *(ushort*)&h;
            Lo[c4 * 4 + k][nl] = *(ushort*)&l;
        }
        *(ushort4*)(XB + ((size_t)t * N + n0 + nl) * D + c4 * 4) = o;
    }
    __syncthreads();

    const int u  = tid & 31;                // uint column (2 nodes: n_lo = 2u, 2u+1)
    const int dr = tid >> 5;                // 0..7
    #pragma unroll
    for (int p = 0; p < 16; ++p) {
        int d = p * 8 + dr;
        uint hv = *(const uint*)&Hi[d][2 * u];
        uint lv = *(const uint*)&Lo[d][2 * u];
        int n_lo = 2 * u;
        int g8   = (n0 + n_lo) >> 3;        // k-group
        int pos  = n_lo & 7;                // 0,2,4,6 (uint stays in-group)
        size_t off = (((size_t)t * 128 + g8) * 128 + d) * 8 + pos;
        *(uint*)(XBT_hi + off) = hv;
        *(uint*)(XBT_lo + off) = lv;
    }
}

// ---------------- Kernel 0b: adj -> 16-bit column bitmask ----------------
__global__ __launch_bounds__(256) void pack_adj(const int* __restrict__ adj,
                                                ushort* __restrict__ Abits) {
    int g = blockIdx.x * 256 + threadIdx.x;   // 0..65535
    int i = g >> 6, w = g & 63;
    const int4* p4 = (const int4*)(adj + (size_t)i * N + w * 16);
    uint m16 = 0;
    #pragma unroll
    for (int v4 = 0; v4 < 4; ++v4) {
        int4 v = p4[v4];
        m16 |= (v.x != 0 ? 1u : 0u) << (v4 * 4 + 0);
        m16 |= (v.y != 0 ? 1u : 0u) << (v4 * 4 + 1);
        m16 |= (v.z != 0 ? 1u : 0u) << (v4 * 4 + 2);
        m16 |= (v.w != 0 ? 1u : 0u) << (v4 * 4 + 3);
    }
    Abits[g] = (ushort)m16;
}

// ---------------- Kernel 1: fused GAT v5 — 3 blocks/CU via LDS-halving ----------------
// r8 grid-REP measured: sustained throughput 24.6us/unit vs 38us production =>
// residency-structure gap (512 blocks = EXACTLY 2/CU, no replacement queue).
// v5: (a) LDS 64KB -> 32KB: Ph/Plo[16][512], Phase 3/4 in two col-halves (waves
// 0-3 write cols 0..511, P4 kq 0..15; swap; waves 4-7 write cols 512..1023, P4
// kq 16..31) — accN chain order unchanged (bit-identical numerics); (b) VGPR
// diet: no 2-deep bfr (ILP proven null r1/r3/r5), adjw per-q; (c)
// __launch_bounds__(512,6) -> VGPR<=84. blocks/CU = min(160/32, 24/8) = 3.
__global__ __launch_bounds__(512, 6) void attn_fused(const ushort* __restrict__ XB,
                                                     const ushort* __restrict__ XBT_hi,
                                                     const ushort* __restrict__ XBT_lo,
                                                     const ushort* __restrict__ Abits,
                                                     float* __restrict__ NF) {
    const int g  = blockIdx.x;
    const int t  = g & 7;              // XCD-aligned timestamp
    const int i0 = (g >> 3) * 16;
    const int tid  = threadIdx.x;
    const int wid  = tid >> 6;         // 0..7
    const int lane = tid & 63;
    const int m    = lane & 15;
    const int quad = lane >> 4;
    const int jbase = wid * 128;       // this wave's 128 score-cols

    __shared__ ushort Ph[16][512];     // swizzled bf16 hi  (one col-half at a time)
    __shared__ ushort Plo[16][512];    // swizzled bf16 lo
    float* red = (float*)&Ph[0][0];    // aliased: [0..127] rowmax, [128..255] rowsum

    const ushort* Xt = XB + (size_t)t * N * D;

    // A-fragments for this row tile (live through Phase 1 only)
    short8 afrag[4];
    {
        const ushort* pa = Xt + (size_t)(i0 + m) * D + quad * 8;
        #pragma unroll
        for (int kq = 0; kq < 4; ++kq) afrag[kq] = *(const short8*)(pa + kq * 32);
    }

    floatx4 acc[8];
    #pragma unroll
    for (int c = 0; c < 8; ++c) acc[c] = (floatx4){0.f, 0.f, 0.f, 0.f};

    // ---- Phase 1: scores, 8 col-tiles per wave (no reg pipeline: TLP covers) ----
    #pragma unroll
    for (int c = 0; c < 8; ++c) {
        const ushort* pb = Xt + (size_t)(jbase + 16 * c + m) * D + quad * 8;
        short8 b0 = *(const short8*)(pb);
        short8 b1 = *(const short8*)(pb + 32);
        short8 b2 = *(const short8*)(pb + 64);
        short8 b3 = *(const short8*)(pb + 96);
        acc[c] = MFMA16(afrag[0], b0, acc[c]);
        acc[c] = MFMA16(afrag[1], b1, acc[c]);
        acc[c] = MFMA16(afrag[2], b2, acc[c]);
        acc[c] = MFMA16(afrag[3], b3, acc[c]);
    }

    // ---- Phase 2: mask + scale (adjw loaded per-q — minimal liveness) ----
    #pragma unroll
    for (int q = 0; q < 4; ++q) {
        short8 adjw = *(const short8*)(Abits + (size_t)(i0 + quad * 4 + q) * 64 + wid * 8);
        #pragma unroll
        for (int c = 0; c < 8; ++c) {
            int aw = (ushort)adjw[c];
            acc[c][q] = ((aw >> m) & 1) ? acc[c][q] * SCALE : -1e12f;
        }
    }

    // ---- Softmax (max order exact; sum regrouped 8-serial + 8-wave, as verified) ----
    float mx[4], inv[4];
    #pragma unroll
    for (int q = 0; q < 4; ++q) {
        float v_ = acc[0][q];
        #pragma unroll
        for (int c = 1; c < 8; ++c) v_ = fmaxf(v_, acc[c][q]);
        v_ = fmaxf(v_, __shfl_xor(v_, 1));
        v_ = fmaxf(v_, __shfl_xor(v_, 2));
        v_ = fmaxf(v_, __shfl_xor(v_, 4));
        v_ = fmaxf(v_, __shfl_xor(v_, 8));
        mx[q] = v_;
    }
    if (m == 0) {
        #pragma unroll
        for (int q = 0; q < 4; ++q) red[wid * 16 + quad * 4 + q] = mx[q];
    }
    __syncthreads();
    #pragma unroll
    for (int q = 0; q < 4; ++q) {
        int r = quad * 4 + q;
        float v_ = red[r];
        #pragma unroll
        for (int w = 1; w < 8; ++w) v_ = fmaxf(v_, red[w * 16 + r]);
        mx[q] = v_;
    }

    float sm[4];
    #pragma unroll
    for (int q = 0; q < 4; ++q) {
        float s_ = 0.f;
        #pragma unroll
        for (int c = 0; c < 8; ++c) {
            float p = __expf(acc[c][q] - mx[q]);
            acc[c][q] = p;
            s_ += p;
        }
        s_ += __shfl_xor(s_, 1);
        s_ += __shfl_xor(s_, 2);
        s_ += __shfl_xor(s_, 4);
        s_ += __shfl_xor(s_, 8);
        sm[q] = s_;
    }
    if (m == 0) {
        #pragma unroll
        for (int q = 0; q < 4; ++q) red[128 + wid * 16 + quad * 4 + q] = sm[q];
    }
    __syncthreads();
    #pragma unroll
    for (int q = 0; q < 4; ++q) {
        int r = quad * 4 + q;
        float s_ = red[128 + r];
        #pragma unroll
        for (int w = 1; w < 8; ++w) s_ += red[128 + w * 16 + r];
        inv[q] = 1.f / s_;
    }
    __syncthreads();   // all red reads done before Ph overwrites the region

    // ---- Phase 4 XBT prefetch prologue (global regs roll across all barriers) ----
    const int dcol = wid * 16 + m;
    const ushort* ph_base = XBT_hi + (size_t)t * 131072 + (size_t)dcol * 8;
    const ushort* pl_base = XBT_lo + (size_t)t * 131072 + (size_t)dcol * 8;
    short8 pfh[4], pfl[4];
#define PF(kq_)                                                                  \
    {                                                                            \
        const size_t off_ = (size_t)((kq_) * 4 + quad) * 1024;                   \
        pfh[(kq_) & 3] = *(const short8*)(ph_base + off_);                       \
        pfl[(kq_) & 3] = *(const short8*)(pl_base + off_);                       \
    }
    PF(0); PF(1); PF(2);

    // ---- Phase 3a: waves 0-3 write P cols 0..511 (compensated bf16, swizzled) ----
    if (wid < 4) {
        #pragma unroll
        for (int q = 0; q < 4; ++q) {
            const int row = quad * 4 + q;
            #pragma unroll
            for (int c = 0; c < 8; ++c) {
                const int col = jbase + 16 * c + m;          // 0..511
                const int sc = ((((col >> 3) ^ (row & 7)) << 3) | (col & 7));
                float p = acc[c][q] * inv[q];
                __hip_bfloat16 h = __float2bfloat16(p);
                float hf = __bfloat162float(h);
                __hip_bfloat16 l = __float2bfloat16(p - hf);
                Ph[row][sc]  = *(ushort*)&h;
                Plo[row][sc] = *(ushort*)&l;
            }
        }
    }
    __syncthreads();

    // ---- Phase 4a: kq = 0..15 (k = 0..511) ----
    floatx4 accN = (floatx4){0.f, 0.f, 0.f, 0.f};
    #pragma unroll
    for (int kq = 0; kq < 16; ++kq) {
        PF(kq + 3);
        const int blk = (((kq * 4 + quad) ^ (m & 7)) << 3);
        short8 ah = *(const short8*)&Ph[m][blk];
        short8 al = *(const short8*)&Plo[m][blk];
        accN = MFMA16(ah, pfh[kq & 3], accN);
        accN = MFMA16(ah, pfl[kq & 3], accN);
        accN = MFMA16(al, pfh[kq & 3], accN);
    }
    __syncthreads();   // all pass-A LDS reads done before overwrite

    // ---- Phase 3b: waves 4-7 write P cols 512..1023 into the same buffer ----
    if (wid >= 4) {
        #pragma unroll
        for (int q = 0; q < 4; ++q) {
            const int row = quad * 4 + q;
            #pragma unroll
            for (int c = 0; c < 8; ++c) {
                const int col = (jbase + 16 * c + m) & 511;  // local 0..511
                const int sc = ((((col >> 3) ^ (row & 7)) << 3) | (col & 7));
                float p = acc[c][q] * inv[q];
                __hip_bfloat16 h = __float2bfloat16(p);
                float hf = __bfloat162float(h);
                __hip_bfloat16 l = __float2bfloat16(p - hf);
                Ph[row][sc]  = *(ushort*)&h;
                Plo[row][sc] = *(ushort*)&l;
            }
        }
    }
    __syncthreads();

    // ---- Phase 4b: kq = 16..31 (k = 512..1023), same accN chain continues ----
    #pragma unroll
    for (int kq = 16; kq < 32; ++kq) {
        if (kq < 29) PF(kq + 3);
        const int blk = ((((kq - 16) * 4 + quad) ^ (m & 7)) << 3);
        short8 ah = *(const short8*)&Ph[m][blk];
        short8 al = *(const short8*)&Plo[m][blk];
        accN = MFMA16(ah, pfh[kq & 3], accN);
        accN = MFMA16(ah, pfl[kq & 3], accN);
        accN = MFMA16(al, pfh[kq & 3], accN);
    }
#undef PF

    float* NFt = NF + (size_t)t * N * D;
    #pragma unroll
    for (int q = 0; q < 4; ++q)
        NFt[(size_t)(i0 + quad * 4 + q) * D + dcol] = accN[q];
}

// ---------------- Kernel 2: fused temporal-gram + sigmoid + broadcast-expand ----------------
// At its write-BW floor (268MB out + 32MB in @ 6.37 TB/s ~= 47us; achieves ~46).
__global__ __launch_bounds__(256) void expand_fused(const float* __restrict__ NF,
                                                    float* __restrict__ out) {
    const int row = blockIdx.x;                 // 0..8191 = b*N + j
    const int b = row >> 10, j = row & 1023;
    const int tid = threadIdx.x;

    __shared__ float F[T][D + 4];               // +4 pad: lanes a=0..7 hit distinct banks
    __shared__ float w[T];

    {   // stage NF[a][j][:] — 256 threads x float4 = 4 KB
        int a = tid >> 5, c4 = (tid & 31) * 4;
        *(float4*)(&F[a][c4]) = *(const float4*)(NF + ((size_t)a * N + j) * D + c4);
    }
    __syncthreads();

    if (tid < T) {                              // 8 lanes: dot(F[tid], F[b])
        float s = 0.f;
        #pragma unroll
        for (int d4 = 0; d4 < 32; ++d4) {
            float4 fa = *(const float4*)(&F[tid][d4 * 4]);
            float4 fb = *(const float4*)(&F[b][d4 * 4]);
            s += fa.x * fb.x + fa.y * fb.y + fa.z * fb.z + fa.w * fb.w;
        }
        w[tid] = 1.f / (1.f + __expf(-s * SCALE));
    }
    __syncthreads();

    floatx4* orow = (floatx4*)(out + (size_t)row * (T * N));
    #pragma unroll
    for (int a = 0; a < T; ++a) {
        float wv = w[a];
        floatx4 v = {wv, wv, wv, wv};
        __builtin_nontemporal_store(v, orow + a * 256 + tid);
    }
}

extern "C" void kernel_launch(void* const* d_in, const int* in_sizes, int n_in,
                              void* d_out, int out_size, void* d_ws, size_t ws_size,
                              hipStream_t stream) {
    const float* X   = (const float*)d_in[0];   // [T,N,D] fp32
    const int*   adj = (const int*)d_in[1];     // [N,N] int32
    float* out = (float*)d_out;                 // [T*N, T*N] fp32

    float*  NF     = (float*)d_ws;                         // T*N*D fp32 (4 MB)
    ushort* XB     = (ushort*)(NF + (size_t)T * N * D);    // T*N*D bf16 (2 MB)
    ushort* XBT_hi = XB + (size_t)T * N * D;               // [t][n/8][d][8] bf16 (2 MB)
    ushort* XBT_lo = XBT_hi + (size_t)T * N * D;           // [t][n/8][d][8] bf16 (2 MB)
    ushort* Abits  = XBT_lo + (size_t)T * N * D;           // [N][64] u16 (128 KB)

    convert_bf16<<<dim3(N / 64, T), 256, 0, stream>>>(X, XB, XBT_hi, XBT_lo);
    pack_adj<<<dim3(N * 64 / 256), 256, 0, stream>>>(adj, Abits);
    attn_fused<<<dim3((N / 16) * T), 512, 0, stream>>>(XB, XBT_hi, XBT_lo, Abits, NF);
    expand_fused<<<dim3(T * N), 256, 0, stream>>>(NF, out);
}

// Round 11
// 307.715 us; speedup vs baseline: 2.6727x; 1.1213x over previous
//
#include <hip/hip_runtime.h>
#include <hip/hip_bf16.h>
#include <math.h>

#define T 8
#define N 1024
#define D 128

constexpr float SCALE = 0.08838834764831845f; // 1/sqrt(128)

typedef __attribute__((ext_vector_type(8))) short short8;   // 8 bf16 (4 VGPRs)
typedef __attribute__((ext_vector_type(4))) float floatx4;  // MFMA acc / native float4

#define MFMA16(a, b, c) __builtin_amdgcn_mfma_f32_16x16x32_bf16((a), (b), (c), 0, 0, 0)

// ---------------- Kernel 0: X fp32 -> XB[t][n][d] bf16 ; XBTb hi/lo [t][n/8][d][8] bf16 ----------
__global__ __launch_bounds__(256) void convert_bf16(const float* __restrict__ X,
                                                    ushort* __restrict__ XB,
                                                    ushort* __restrict__ XBT_hi,
                                                    ushort* __restrict__ XBT_lo) {
    const int t  = blockIdx.y;
    const int n0 = blockIdx.x * 64;
    const int tid = threadIdx.x;

    __shared__ ushort Hi[128][66];
    __shared__ ushort Lo[128][66];

    #pragma unroll
    for (int r = 0; r < 8; ++r) {
        int idx = r * 256 + tid;            // 0..2047 float4 slots of this tile
        int nl  = idx >> 5;                 // 0..63  local node
        int c4  = idx & 31;                 // float4 column
        float4 v = *(const float4*)(X + ((size_t)t * N + n0 + nl) * D + c4 * 4);
        float vv[4] = {v.x, v.y, v.z, v.w};
        ushort4 o; ushort* op = (ushort*)&o;
        #pragma unroll
        for (int k = 0; k < 4; ++k) {
            __hip_bfloat16 h = __float2bfloat16(vv[k]);
            float hf = __bfloat162float(h);
            __hip_bfloat16 l = __float2bfloat16(vv[k] - hf);
            op[k] = *(ushort*)&h;
            Hi[c4 * 4 + k][nl] = *(ushort*)&h;
            Lo[c4 * 4 + k][nl] = *(ushort*)&l;
        }
        *(ushort4*)(XB + ((size_t)t * N + n0 + nl) * D + c4 * 4) = o;
    }
    __syncthreads();

    const int u  = tid & 31;                // uint column (2 nodes: n_lo = 2u, 2u+1)
    const int dr = tid >> 5;                // 0..7
    #pragma unroll
    for (int p = 0; p < 16; ++p) {
        int d = p * 8 + dr;
        uint hv = *(const uint*)&Hi[d][2 * u];
        uint lv = *(const uint*)&Lo[d][2 * u];
        int n_lo = 2 * u;
        int g8   = (n0 + n_lo) >> 3;        // k-group
        int pos  = n_lo & 7;                // 0,2,4,6 (uint stays in-group)
        size_t off = (((size_t)t * 128 + g8) * 128 + d) * 8 + pos;
        *(uint*)(XBT_hi + off) = hv;
        *(uint*)(XBT_lo + off) = lv;
    }
}

// ---------------- Kernel 0b: adj -> 16-bit column bitmask ----------------
__global__ __launch_bounds__(256) void pack_adj(const int* __restrict__ adj,
                                                ushort* __restrict__ Abits) {
    int g = blockIdx.x * 256 + threadIdx.x;   // 0..65535
    int i = g >> 6, w = g & 63;
    const int4* p4 = (const int4*)(adj + (size_t)i * N + w * 16);
    uint m16 = 0;
    #pragma unroll
    for (int v4 = 0; v4 < 4; ++v4) {
        int4 v = p4[v4];
        m16 |= (v.x != 0 ? 1u : 0u) << (v4 * 4 + 0);
        m16 |= (v.y != 0 ? 1u : 0u) << (v4 * 4 + 1);
        m16 |= (v.z != 0 ? 1u : 0u) << (v4 * 4 + 2);
        m16 |= (v.w != 0 ? 1u : 0u) << (v4 * 4 + 3);
    }
    Abits[g] = (ushort)m16;
}

// ---------------- Kernel 1: fused GAT v4 — VERIFIED BEST (r6, 308.6us total) ----------------
// Final form. Session evidence: 512 blocks = exactly full residency (2 blk/CU x
// 256 CU); all blocks run phase-locked, single-generation latency 38us. The
// 24.6us/unit sustained rate (r8 5x-grid) needs block-queue phase stagger that
// this fixed 512-block decomposition cannot provide; raising per-CU CAPACITY
// (r9: 32KB LDS + 84 VGPR) cannot raise RESIDENCY and regressed via spills +
// half-wave serialization. Further gains require online-softmax restructuring
// with numeric-order changes (absmax risk) — out of scope.
__global__ __launch_bounds__(512, 4) void attn_fused(const ushort* __restrict__ XB,
                                                     const ushort* __restrict__ XBT_hi,
                                                     const ushort* __restrict__ XBT_lo,
                                                     const ushort* __restrict__ Abits,
                                                     float* __restrict__ NF) {
    const int g  = blockIdx.x;
    const int t  = g & 7;              // XCD-aligned timestamp
    const int i0 = (g >> 3) * 16;
    const int tid  = threadIdx.x;
    const int wid  = tid >> 6;         // 0..7
    const int lane = tid & 63;
    const int m    = lane & 15;
    const int quad = lane >> 4;
    const int jbase = wid * 128;       // this wave's 128 score-cols

    __shared__ ushort Ph[16][1024];    // swizzled bf16 hi
    __shared__ ushort Plo[16][1024];   // swizzled bf16 lo
    float* red = (float*)&Ph[0][0];    // aliased: [0..127] rowmax, [128..255] rowsum

    const ushort* Xt = XB + (size_t)t * N * D;

    // A-fragments for this row tile (live through Phase 1 only)
    short8 afrag[4];
    {
        const ushort* pa = Xt + (size_t)(i0 + m) * D + quad * 8;
        #pragma unroll
        for (int kq = 0; kq < 4; ++kq) afrag[kq] = *(const short8*)(pa + kq * 32);
    }

    floatx4 acc[8];
    #pragma unroll
    for (int c = 0; c < 8; ++c) acc[c] = (floatx4){0.f, 0.f, 0.f, 0.f};

    // ---- Phase 1: scores (2-deep pipelined B loads), 8 col-tiles per wave ----
    short8 bfr[2][4];
    {
        const ushort* pb = Xt + (size_t)(jbase + m) * D + quad * 8;
        bfr[0][0] = *(const short8*)(pb);
        bfr[0][1] = *(const short8*)(pb + 32);
        bfr[0][2] = *(const short8*)(pb + 64);
        bfr[0][3] = *(const short8*)(pb + 96);
    }
    #pragma unroll
    for (int c = 0; c < 8; ++c) {
        if (c < 7) {
            const ushort* pb = Xt + (size_t)(jbase + 16 * (c + 1) + m) * D + quad * 8;
            bfr[(c + 1) & 1][0] = *(const short8*)(pb);
            bfr[(c + 1) & 1][1] = *(const short8*)(pb + 32);
            bfr[(c + 1) & 1][2] = *(const short8*)(pb + 64);
            bfr[(c + 1) & 1][3] = *(const short8*)(pb + 96);
        }
        acc[c] = MFMA16(afrag[0], bfr[c & 1][0], acc[c]);
        acc[c] = MFMA16(afrag[1], bfr[c & 1][1], acc[c]);
        acc[c] = MFMA16(afrag[2], bfr[c & 1][2], acc[c]);
        acc[c] = MFMA16(afrag[3], bfr[c & 1][3], acc[c]);
    }

    // ---- Phase 2: mask + scale (adjw loaded here — short live range) ----
    short8 adjw[4];   // words wid*8 .. wid*8+7 of each owned row
    #pragma unroll
    for (int q = 0; q < 4; ++q)
        adjw[q] = *(const short8*)(Abits + (size_t)(i0 + quad * 4 + q) * 64 + wid * 8);
    #pragma unroll
    for (int q = 0; q < 4; ++q) {
        #pragma unroll
        for (int c = 0; c < 8; ++c) {
            int aw = (ushort)adjw[q][c];
            acc[c][q] = ((aw >> m) & 1) ? acc[c][q] * SCALE : -1e12f;
        }
    }

    // ---- Softmax (max order exact; sum regrouped 8-serial + 8-wave) ----
    float mx[4], inv[4];
    #pragma unroll
    for (int q = 0; q < 4; ++q) {
        float v_ = acc[0][q];
        #pragma unroll
        for (int c = 1; c < 8; ++c) v_ = fmaxf(v_, acc[c][q]);
        v_ = fmaxf(v_, __shfl_xor(v_, 1));
        v_ = fmaxf(v_, __shfl_xor(v_, 2));
        v_ = fmaxf(v_, __shfl_xor(v_, 4));
        v_ = fmaxf(v_, __shfl_xor(v_, 8));
        mx[q] = v_;
    }
    if (m == 0) {
        #pragma unroll
        for (int q = 0; q < 4; ++q) red[wid * 16 + quad * 4 + q] = mx[q];
    }
    __syncthreads();
    #pragma unroll
    for (int q = 0; q < 4; ++q) {
        int r = quad * 4 + q;
        float v_ = red[r];
        #pragma unroll
        for (int w = 1; w < 8; ++w) v_ = fmaxf(v_, red[w * 16 + r]);
        mx[q] = v_;
    }

    float sm[4];
    #pragma unroll
    for (int q = 0; q < 4; ++q) {
        float s_ = 0.f;
        #pragma unroll
        for (int c = 0; c < 8; ++c) {
            float p = __expf(acc[c][q] - mx[q]);
            acc[c][q] = p;
            s_ += p;
        }
        s_ += __shfl_xor(s_, 1);
        s_ += __shfl_xor(s_, 2);
        s_ += __shfl_xor(s_, 4);
        s_ += __shfl_xor(s_, 8);
        sm[q] = s_;
    }
    if (m == 0) {
        #pragma unroll
        for (int q = 0; q < 4; ++q) red[128 + wid * 16 + quad * 4 + q] = sm[q];
    }
    __syncthreads();
    #pragma unroll
    for (int q = 0; q < 4; ++q) {
        int r = quad * 4 + q;
        float s_ = red[128 + r];
        #pragma unroll
        for (int w = 1; w < 8; ++w) s_ += red[128 + w * 16 + r];
        inv[q] = 1.f / s_;
    }
    __syncthreads();   // all red reads done before Ph overwrites the region

    // ---- Phase 3: P -> LDS (compensated bf16, XOR-swizzled 16B blocks) ----
    #pragma unroll
    for (int q = 0; q < 4; ++q) {
        const int row = quad * 4 + q;
        #pragma unroll
        for (int c = 0; c < 8; ++c) {
            const int col = jbase + 16 * c + m;
            const int sc = ((((col >> 3) ^ (row & 7)) << 3) | (col & 7));
            float p = acc[c][q] * inv[q];
            __hip_bfloat16 h = __float2bfloat16(p);
            float hf = __bfloat162float(h);
            __hip_bfloat16 l = __float2bfloat16(p - hf);
            Ph[row][sc]  = *(ushort*)&h;
            Plo[row][sc] = *(ushort*)&l;
        }
    }
    __syncthreads();

    // ---- Phase 4: NF = P * X (3-term compensated MFMA, depth-3 rolling prefetch) ----
    const int dcol = wid * 16 + m;
    const ushort* ph_base = XBT_hi + (size_t)t * 131072 + (size_t)dcol * 8;
    const ushort* pl_base = XBT_lo + (size_t)t * 131072 + (size_t)dcol * 8;
    short8 pfh[4], pfl[4];
#define PF(kq_)                                                                  \
    {                                                                            \
        const size_t off_ = (size_t)((kq_) * 4 + quad) * 1024;                   \
        pfh[(kq_) & 3] = *(const short8*)(ph_base + off_);                       \
        pfl[(kq_) & 3] = *(const short8*)(pl_base + off_);                       \
    }
    PF(0); PF(1); PF(2);

    floatx4 accN = (floatx4){0.f, 0.f, 0.f, 0.f};
    #pragma unroll
    for (int kq = 0; kq < 32; ++kq) {
        if (kq < 29) PF(kq + 3);
        const int blk = (((kq * 4 + quad) ^ (m & 7)) << 3);
        short8 ah = *(const short8*)&Ph[m][blk];
        short8 al = *(const short8*)&Plo[m][blk];
        accN = MFMA16(ah, pfh[kq & 3], accN);
        accN = MFMA16(ah, pfl[kq & 3], accN);
        accN = MFMA16(al, pfh[kq & 3], accN);
    }
#undef PF

    float* NFt = NF + (size_t)t * N * D;
    #pragma unroll
    for (int q = 0; q < 4; ++q)
        NFt[(size_t)(i0 + quad * 4 + q) * D + dcol] = accN[q];
}

// ---------------- Kernel 2: fused temporal-gram + sigmoid + broadcast-expand ----------------
// At its write-BW floor (268MB out + 32MB in @ 6.4 TB/s ~= 47us; proven by r0/r1
// A/B: structurally different versions time identically).
__global__ __launch_bounds__(256) void expand_fused(const float* __restrict__ NF,
                                                    float* __restrict__ out) {
    const int row = blockIdx.x;                 // 0..8191 = b*N + j
    const int b = row >> 10, j = row & 1023;
    const int tid = threadIdx.x;

    __shared__ float F[T][D + 4];               // +4 pad: lanes a=0..7 hit distinct banks
    __shared__ float w[T];

    {   // stage NF[a][j][:] — 256 threads x float4 = 4 KB
        int a = tid >> 5, c4 = (tid & 31) * 4;
        *(float4*)(&F[a][c4]) = *(const float4*)(NF + ((size_t)a * N + j) * D + c4);
    }
    __syncthreads();

    if (tid < T) {                              // 8 lanes: dot(F[tid], F[b])
        float s = 0.f;
        #pragma unroll
        for (int d4 = 0; d4 < 32; ++d4) {
            float4 fa = *(const float4*)(&F[tid][d4 * 4]);
            float4 fb = *(const float4*)(&F[b][d4 * 4]);
            s += fa.x * fb.x + fa.y * fb.y + fa.z * fb.z + fa.w * fb.w;
        }
        w[tid] = 1.f / (1.f + __expf(-s * SCALE));
    }
    __syncthreads();

    floatx4* orow = (floatx4*)(out + (size_t)row * (T * N));
    #pragma unroll
    for (int a = 0; a < T; ++a) {
        float wv = w[a];
        floatx4 v = {wv, wv, wv, wv};
        __builtin_nontemporal_store(v, orow + a * 256 + tid);
    }
}

extern "C" void kernel_launch(void* const* d_in, const int* in_sizes, int n_in,
                              void* d_out, int out_size, void* d_ws, size_t ws_size,
                              hipStream_t stream) {
    const float* X   = (const float*)d_in[0];   // [T,N,D] fp32
    const int*   adj = (const int*)d_in[1];     // [N,N] int32
    float* out = (float*)d_out;                 // [T*N, T*N] fp32

    float*  NF     = (float*)d_ws;                         // T*N*D fp32 (4 MB)
    ushort* XB     = (ushort*)(NF + (size_t)T * N * D);    // T*N*D bf16 (2 MB)
    ushort* XBT_hi = XB + (size_t)T * N * D;               // [t][n/8][d][8] bf16 (2 MB)
    ushort* XBT_lo = XBT_hi + (size_t)T * N * D;           // [t][n/8][d][8] bf16 (2 MB)
    ushort* Abits  = XBT_lo + (size_t)T * N * D;           // [N][64] u16 (128 KB)

    convert_bf16<<<dim3(N / 64, T), 256, 0, stream>>>(X, XB, XBT_hi, XBT_lo);
    pack_adj<<<dim3(N * 64 / 256), 256, 0, stream>>>(adj, Abits);
    attn_fused<<<dim3((N / 16) * T), 512, 0, stream>>>(XB, XBT_hi, XBT_lo, Abits, NF);
    expand_fused<<<dim3(T * N), 256, 0, stream>>>(NF, out);
}